// Round 4
// baseline (160.934 us; speedup 1.0000x reference)
//
#include <hip/hip_runtime.h>
#include <math.h>

#define BATCH 64
#define DIM 512
#define NPATCH 128
#define SSZ 64

typedef float f32x4 __attribute__((ext_vector_type(4)));

// ---------------------------------------------------------------------------
// Single fused kernel, v2. One block = 4 consecutive images (bp = blk*4+q),
// 256 threads = 4 waves. Output region per block = 64 KiB contiguous.
//
// Phase 1 (GEMM): 60 dots of length 512 (4 patches x 15 rows; rows 0..8 are
//   mask logits, 9..14 theta). Thread t: slot s=t>>2 (q=s>>4 image, r=s&15
//   row; r==15 idle), lane c=t&3 covers float4 indices c+4k, k=0..31.
//   4-accumulator FMA chain, 2-step shfl_xor reduce within the 4-lane group,
//   epilogue (1-sigmoid)*noise / +bt on c==0, -> 64-word LDS.
//   GEMM VALU is ~1 us device-wide; W re-read per-b (~250 MB L2) pipelines
//   under phase 2's store stream. No workspace, no second launch.
//
// Phase 2 (sampler, verbatim from verified r3): wave w owns image q=w and
//   walks its 16 KiB LINEARLY: 16 units x contiguous 1-KiB wave store at
//   strictly increasing addresses (the 6.3 TB/s fill's access shape).
//   Record broadcast via LDS read + __shfl. hat(t)=max(0,1-|t|)=
//   v_med3(0,1+t,1-t); per-unit base ix/iy by fmaf(a,step,base) (no drift).
// ---------------------------------------------------------------------------
__global__ __launch_bounds__(256) void k_fused2(
    const float* __restrict__ z, const float* __restrict__ Wm,
    const float* __restrict__ bm, const float* __restrict__ Wt,
    const float* __restrict__ bt, const float* __restrict__ noise,
    float* __restrict__ out) {
  __shared__ float sm[64];  // [q][r] records: 9 masks + 6 theta (+1 pad slot)

  const int t = threadIdx.x;
  const int blk = blockIdx.x;          // 0..2047
  const int b = blk >> 5;              // batch
  const int p0 = (blk & 31) << 2;      // first patch of the quad

  // ---- Phase 1 ----
  {
    const int s = t >> 2;              // slot 0..63
    const int c = t & 3;               // lane within row-group
    const int q = s >> 4;              // image 0..3
    const int r = s & 15;              // row 0..15 (15 idle)
    const int rr = (r < 15) ? r : 14;  // clamp for harmless dup loads
    const int p = p0 + q;

    const float* __restrict__ wrow =
        (rr < 9) ? (Wm + (size_t)(p * 9 + rr) * DIM)
                 : (Wt + (size_t)(p * 6 + (rr - 9)) * DIM);
    const f32x4* __restrict__ wq = (const f32x4*)wrow + c;
    const f32x4* __restrict__ zq = (const f32x4*)(z + (size_t)b * DIM) + c;

    float a0 = 0.0f, a1 = 0.0f, a2 = 0.0f, a3 = 0.0f;
#pragma unroll 8
    for (int k = 0; k < 32; ++k) {
      const f32x4 wv = wq[k << 2];
      const f32x4 zv = zq[k << 2];
      a0 = fmaf(wv.x, zv.x, a0);
      a1 = fmaf(wv.y, zv.y, a1);
      a2 = fmaf(wv.z, zv.z, a2);
      a3 = fmaf(wv.w, zv.w, a3);
    }
    float acc = (a0 + a1) + (a2 + a3);
    acc += __shfl_xor(acc, 1);
    acc += __shfl_xor(acc, 2);

    if (c == 0 && r < 15) {
      float v;
      if (r < 9) {
        // 1 - sigmoid(x) = 1/(1+exp(x)), then patch noise
        v = (1.0f / (1.0f + expf(acc + bm[p * 9 + r]))) * noise[r];
      } else {
        v = acc + bt[p * 6 + (r - 9)];
      }
      sm[s] = v;
    }
  }
  __syncthreads();

  // ---- Phase 2: wave w streams image (blk*4 + w) ----
  const int w = t >> 6;     // wave id = image within quad
  const int lane = t & 63;

  const float rec = sm[(w << 4) + (lane & 15)];
  const float m00 = __shfl(rec, 0), m01 = __shfl(rec, 1), m02 = __shfl(rec, 2);
  const float m10 = __shfl(rec, 3), m11 = __shfl(rec, 4), m12 = __shfl(rec, 5);
  const float m20 = __shfl(rec, 6), m21 = __shfl(rec, 7), m22 = __shfl(rec, 8);
  const float th0 = __shfl(rec, 9), th1 = __shfl(rec, 10), th2 = __shfl(rec, 11);
  const float th3 = __shfl(rec, 12), th4 = __shfl(rec, 13), th5 = __shfl(rec, 14);

  const int w4 = (lane & 15) << 2;  // 4 consecutive w-pixels per lane
  const int rsub = lane >> 4;       // sub-row 0..3 within a 4-row unit
  const float cx0 = (w4 + 0.5f) * (1.0f / 32.0f) - 1.0f;
  const float cy0 = (rsub + 0.5f) * (1.0f / 32.0f) - 1.0f;
  const float dix = th0 * (1.5f / 32.0f);   // per-w step
  const float diy = th3 * (1.5f / 32.0f);
  const float dAx = th1 * (1.5f * 0.125f);  // per-unit (4-row) step
  const float dAy = th4 * (1.5f * 0.125f);
  const float ixb0 = fmaf(1.5f, fmaf(th0, cx0, fmaf(th1, cy0, th2)), 1.0f);
  const float iyb0 = fmaf(1.5f, fmaf(th3, cx0, fmaf(th4, cy0, th5)), 1.0f);

  float* op = out + (((size_t)(blk << 2) + w) << 12) + (rsub << 6) + w4;

#pragma unroll 2
  for (int a = 0; a < 16; ++a) {
    float ix = fmaf((float)a, dAx, ixb0);
    float iy = fmaf((float)a, dAy, iyb0);
    f32x4 rv;
#pragma unroll
    for (int j = 0; j < 4; ++j) {
      const float ax = ix + 1.0f, bx = 1.0f - ix;  // hat arms, sum == 2
      const float ay = iy + 1.0f, by = 1.0f - iy;
      const float wx0 = __builtin_amdgcn_fmed3f(0.0f, ax, bx);
      const float wx1 = __builtin_amdgcn_fmed3f(0.0f, ax - 1.0f, bx + 1.0f);
      const float wx2 = __builtin_amdgcn_fmed3f(0.0f, ax - 2.0f, bx + 2.0f);
      const float wy0 = __builtin_amdgcn_fmed3f(0.0f, ay, by);
      const float wy1 = __builtin_amdgcn_fmed3f(0.0f, ay - 1.0f, by + 1.0f);
      const float wy2 = __builtin_amdgcn_fmed3f(0.0f, ay - 2.0f, by + 2.0f);
      const float s0 = fmaf(m02, wx2, fmaf(m01, wx1, m00 * wx0));
      const float s1 = fmaf(m12, wx2, fmaf(m11, wx1, m10 * wx0));
      const float s2 = fmaf(m22, wx2, fmaf(m21, wx1, m20 * wx0));
      rv[j] = fmaf(wy2, s2, fmaf(wy1, s1, wy0 * s0));
      ix += dix;
      iy += diy;
    }
    *(f32x4*)op = rv;   // contiguous 1 KiB per wave, sequential in a
    op += 256;          // next 4-row unit = 256 floats = 1 KiB
  }
}

extern "C" void kernel_launch(void* const* d_in, const int* in_sizes, int n_in,
                              void* d_out, int out_size, void* d_ws, size_t ws_size,
                              hipStream_t stream) {
  const float* z     = (const float*)d_in[0];
  const float* Wm    = (const float*)d_in[1];
  const float* bm    = (const float*)d_in[2];
  const float* Wt    = (const float*)d_in[3];
  const float* bt    = (const float*)d_in[4];
  const float* noise = (const float*)d_in[5];
  float* out = (float*)d_out;

  // one block per 4 images; single dispatch, no workspace
  hipLaunchKernelGGL(k_fused2, dim3(BATCH * NPATCH / 4), dim3(256), 0, stream,
                     z, Wm, bm, Wt, bt, noise, out);
}